// Round 15
// baseline (470.051 us; speedup 1.0000x reference)
//
#include <hip/hip_runtime.h>
#include <hip/hip_cooperative_groups.h>

namespace cg = cooperative_groups;

#define NN 100000
#define NE 1600000
#define EPSV 1e-5f
#define NTILE 1563          // ceil(NN/64)
#define TGRID 512           // k_tail coop grid; block b owns tiles b + k*512

typedef float f32x4 __attribute__((ext_vector_type(4)));
typedef short s16x8 __attribute__((ext_vector_type(8)));

__device__ __forceinline__ unsigned short f2bf(float f) {
  unsigned int u = __float_as_uint(f);
  u += 0x7fffu + ((u >> 16) & 1u);   // round-to-nearest-even
  return (unsigned short)(u >> 16);
}

__device__ __forceinline__ float bf2f(unsigned short s) {
  return __uint_as_float(((unsigned int)s) << 16);
}

__device__ __forceinline__ ushort4 pack4(float4 v) {
  ushort4 s;
  s.x = f2bf(v.x); s.y = f2bf(v.y); s.z = f2bf(v.z); s.w = f2bf(v.w);
  return s;
}

// ---- K1: bucket (4/5 of blocks) ∥ g1a partial GEMM (1/5) ----------------------
__global__ __launch_bounds__(256) void k_bucket_g1a(
    const int* __restrict__ ei, int* __restrict__ cnt, int* __restrict__ eids,
    const float4* __restrict__ x4, const float4* __restrict__ state4,
    const int* __restrict__ batch, const float4* __restrict__ w14,
    f32x4* __restrict__ ph) {
  __shared__ unsigned short lx[64][136];   // x(0..63) + state(64..127) per node
  __shared__ unsigned short lw[64][136];   // W1 x-cols + state-cols per out-row
  const int idx = blockIdx.x;
  const int tid = threadIdx.x;
  const bool is_g1a = ((idx % 5) == 2) && (idx / 5 < NTILE);
  if (!is_g1a) {
    int nga = idx / 5 + (((idx % 5) > 2) ? 1 : 0);   // g1a blocks before idx
    if (nga > NTILE) nga = NTILE;
    int e = (idx - nga) * 256 + tid;                 // bucket_id * 256 + tid
    int src = ei[e];
    int pos = atomicAdd(&cnt[src], 1);
    if (pos < 64) eids[(size_t)src * 64 + pos] = e;
    return;
  }
  const int tile = idx / 5;
  const int nodeBase = tile * 64;
#pragma unroll
  for (int i = 0; i < 4; ++i) {            // W1: x-part q0..15, state-part q32..47
    int t = tid + i * 256;
    int j = t >> 4, q = t & 15;
    *(ushort4*)&lw[j][q * 4]      = pack4(w14[j * 48 + q]);
    *(ushort4*)&lw[j][64 + q * 4] = pack4(w14[j * 48 + 32 + q]);
  }
#pragma unroll
  for (int i = 0; i < 4; ++i) {            // node tile: x + state[batch]
    int t = tid + i * 256;
    int node = t >> 4, q = t & 15;
    int g = nodeBase + node;
    float4 vx = {0,0,0,0}, vs = {0,0,0,0};
    if (g < NN) {
      vx = x4[(size_t)g * 16 + q];
      vs = state4[batch[g] * 16 + q];
    }
    *(ushort4*)&lx[node][q * 4]      = pack4(vx);
    *(ushort4*)&lx[node][64 + q * 4] = pack4(vs);
  }
  __syncthreads();
  const int lane = tid & 63, w = tid >> 6;
  const int rg = lane >> 4, ci = lane & 15;
  f32x4 acc[4] = {{0,0,0,0},{0,0,0,0},{0,0,0,0},{0,0,0,0}};
#pragma unroll
  for (int s = 0; s < 4; ++s) {            // 128 packed k-cols
    int k0 = 32 * s + rg * 8;
    s16x8 a = *(const s16x8*)&lx[w * 16 + ci][k0];
#pragma unroll
    for (int c = 0; c < 4; ++c) {
      s16x8 b = *(const s16x8*)&lw[c * 16 + ci][k0];
      acc[c] = __builtin_amdgcn_mfma_f32_16x16x32_bf16(a, b, acc[c], 0, 0, 0);
    }
  }
#pragma unroll
  for (int c = 0; c < 4; ++c)
    ph[(size_t)tile * 1024 + tid * 4 + c] = acc[c];
}

// ---- K2: fused gather-mean + g1b (identical to r13) ---------------------------
__global__ __launch_bounds__(256) void k_gather_g1b(
    const int* __restrict__ cnt, const int* __restrict__ eids,
    const float4* __restrict__ ea4,
    const float4* __restrict__ w14, const float* __restrict__ b1,
    const f32x4* __restrict__ ph, unsigned short* __restrict__ h1,
    float* __restrict__ Sout, float* __restrict__ Qout) {
  __shared__ unsigned short lv[64][72];    // vmean tile
  __shared__ unsigned short lwv[64][72];   // W1 vm-cols; reused as out-tile
  __shared__ float ssum[64], ssq[64];
  const int tid = threadIdx.x;
  const int tile = blockIdx.x;
  const int nodeBase = tile * 64;
  if (tid < 64) { ssum[tid] = 0.f; ssq[tid] = 0.f; }
#pragma unroll
  for (int i = 0; i < 4; ++i) {            // W1 vm-cols (k=64..127)
    int t = tid + i * 256;
    int j = t >> 4, q = t & 15;
    *(ushort4*)&lwv[j][q * 4] = pack4(w14[j * 48 + 16 + q]);
  }
  const int lane = tid & 63, w = tid >> 6;
  const int grp = lane >> 4, q = lane & 15;
  for (int k = 0; k < 16; ++k) {           // 16 nodes per wave
    int n = nodeBase + w * 16 + k;
    float ax = 0.f, ay = 0.f, az = 0.f, aw = 0.f;
    int c = 0;
    if (n < NN) {
      const int* elist = eids + (size_t)n * 64;
      c = cnt[n];
      int m = c < 64 ? c : 64;
      int rm = m - 1;
      {
        int r0 = grp,      r1 = 4 + grp,  r2 = 8 + grp,  r3 = 12 + grp;
        int r4 = 16 + grp, r5 = 20 + grp, r6 = 24 + grp, r7 = 28 + grp;
        int i0 = elist[r0 < m ? r0 : rm];
        int i1 = elist[r1 < m ? r1 : rm];
        int i2 = elist[r2 < m ? r2 : rm];
        int i3 = elist[r3 < m ? r3 : rm];
        int i4 = elist[r4 < m ? r4 : rm];
        int i5 = elist[r5 < m ? r5 : rm];
        int i6 = elist[r6 < m ? r6 : rm];
        int i7 = elist[r7 < m ? r7 : rm];
        float4 v0 = ea4[(size_t)i0 * 16 + q];
        float4 v1 = ea4[(size_t)i1 * 16 + q];
        float4 v2 = ea4[(size_t)i2 * 16 + q];
        float4 v3 = ea4[(size_t)i3 * 16 + q];
        float4 v4 = ea4[(size_t)i4 * 16 + q];
        float4 v5 = ea4[(size_t)i5 * 16 + q];
        float4 v6 = ea4[(size_t)i6 * 16 + q];
        float4 v7 = ea4[(size_t)i7 * 16 + q];
        float m0 = r0 < m ? 1.f : 0.f, m1 = r1 < m ? 1.f : 0.f;
        float m2 = r2 < m ? 1.f : 0.f, m3 = r3 < m ? 1.f : 0.f;
        ax += m0 * v0.x + m1 * v1.x + m2 * v2.x + m3 * v3.x;
        ay += m0 * v0.y + m1 * v1.y + m2 * v2.y + m3 * v3.y;
        az += m0 * v0.z + m1 * v1.z + m2 * v2.z + m3 * v3.z;
        aw += m0 * v0.w + m1 * v1.w + m2 * v2.w + m3 * v3.w;
        float m4 = r4 < m ? 1.f : 0.f, m5 = r5 < m ? 1.f : 0.f;
        float m6 = r6 < m ? 1.f : 0.f, m7 = r7 < m ? 1.f : 0.f;
        ax += m4 * v4.x + m5 * v5.x + m6 * v6.x + m7 * v7.x;
        ay += m4 * v4.y + m5 * v5.y + m6 * v6.y + m7 * v7.y;
        az += m4 * v4.z + m5 * v5.z + m6 * v6.z + m7 * v7.z;
        aw += m4 * v4.w + m5 * v5.w + m6 * v6.w + m7 * v7.w;
      }
      if (m > 32) {                        // rare tail (P ~ 2e-4)
        for (int e = 32; e < m; e += 16) {
          int r0 = e + grp, r1 = e + 4 + grp, r2 = e + 8 + grp, r3 = e + 12 + grp;
          int i0 = elist[r0 < m ? r0 : rm];
          int i1 = elist[r1 < m ? r1 : rm];
          int i2 = elist[r2 < m ? r2 : rm];
          int i3 = elist[r3 < m ? r3 : rm];
          float4 v0 = ea4[(size_t)i0 * 16 + q];
          float4 v1 = ea4[(size_t)i1 * 16 + q];
          float4 v2 = ea4[(size_t)i2 * 16 + q];
          float4 v3 = ea4[(size_t)i3 * 16 + q];
          float m0 = r0 < m ? 1.f : 0.f, m1 = r1 < m ? 1.f : 0.f;
          float m2 = r2 < m ? 1.f : 0.f, m3 = r3 < m ? 1.f : 0.f;
          ax += m0 * v0.x + m1 * v1.x + m2 * v2.x + m3 * v3.x;
          ay += m0 * v0.y + m1 * v1.y + m2 * v2.y + m3 * v3.y;
          az += m0 * v0.z + m1 * v1.z + m2 * v2.z + m3 * v3.z;
          aw += m0 * v0.w + m1 * v1.w + m2 * v2.w + m3 * v3.w;
        }
      }
    }
    ax += __shfl_xor(ax, 16); ay += __shfl_xor(ay, 16);
    az += __shfl_xor(az, 16); aw += __shfl_xor(aw, 16);
    ax += __shfl_xor(ax, 32); ay += __shfl_xor(ay, 32);
    az += __shfl_xor(az, 32); aw += __shfl_xor(aw, 32);
    if (lane < 16) {
      float inv = 1.0f / fmaxf((float)c, 1.0f);
      float4 r; r.x = ax * inv; r.y = ay * inv; r.z = az * inv; r.w = aw * inv;
      *(ushort4*)&lv[w * 16 + k][lane * 4] = pack4(r);
    }
  }
  __syncthreads();
  const int rg = lane >> 4, ci = lane & 15;
  f32x4 acc[4];
#pragma unroll
  for (int cc = 0; cc < 4; ++cc) acc[cc] = ph[(size_t)tile * 1024 + tid * 4 + cc];
#pragma unroll
  for (int s = 0; s < 2; ++s) {
    int k0 = 32 * s + rg * 8;
    s16x8 a = *(const s16x8*)&lv[w * 16 + ci][k0];
#pragma unroll
    for (int cc = 0; cc < 4; ++cc) {
      s16x8 b = *(const s16x8*)&lwv[cc * 16 + ci][k0];
      acc[cc] = __builtin_amdgcn_mfma_f32_16x16x32_bf16(a, b, acc[cc], 0, 0, 0);
    }
  }
  __syncthreads();                         // lwv reads done; reuse as out-tile
  unsigned short (*lo)[72] = (unsigned short(*)[72])lwv;
#pragma unroll
  for (int cc = 0; cc < 4; ++cc) {
    int col = cc * 16 + ci;
    float bb = b1[col];
    float ls = 0.f, lq = 0.f;
#pragma unroll
    for (int r = 0; r < 4; ++r) {
      int row = w * 16 + rg * 4 + r;
      float v = fmaxf(acc[cc][r] + bb, 0.f);
      lo[row][col] = f2bf(v);
      if (nodeBase + row < NN) { ls += v; lq += v * v; }
    }
    atomicAdd(&ssum[col], ls);
    atomicAdd(&ssq[col], lq);
  }
  __syncthreads();
#pragma unroll
  for (int i = 0; i < 2; ++i) {            // coalesced 16B stores
    int t = tid + i * 256;
    int row = t >> 3, q2 = t & 7;
    int g = nodeBase + row;
    if (g < NN) *(s16x8*)&h1[(size_t)g * 64 + q2 * 8] = *(const s16x8*)&lo[row][q2 * 8];
  }
  if (tid < 64) {
    unsafeAtomicAdd(&Sout[tid], ssum[tid]);
    unsafeAtomicAdd(&Qout[tid], ssq[tid]);
  }
}

// ---- K3: cooperative tail: gemm2 -> gemm3 -> BN3, h tiles resident in LDS -----
struct TailArgs {
  const s16x8* h1;
  const float *W2, *b2, *g1, *be1;
  const float *W3, *b3, *g2, *be2;
  const float *g3, *be3;
  float *S1, *Q1, *S2, *Q2, *S3, *Q3;
  float4* out4;
};

__global__ __launch_bounds__(256, 2) void k_tail(TailArgs A) {
  __shared__ unsigned short ht[4][64][72];   // resident h tiles (bf16), 36.9 KB
  __shared__ unsigned short lwf[64][72];     // folded W bf16 (reused per phase)
  __shared__ float lA[64], lC[64], ld[64], red[256], ssum[64], ssq[64];
  cg::grid_group grid = cg::this_grid();
  const int tid = threadIdx.x;
  const int b = blockIdx.x;                  // tiles b + k*TGRID, k=0..nt-1
  const int lane = tid & 63, w = tid >> 6;
  const int rg = lane >> 4, ci = lane & 15;
  const int nt = (b + 3 * TGRID < NTILE) ? 4 : 3;   // 512*3=1536<=1563; b<27 get 4

  // ---- stage h1 tiles into LDS ----
  for (int t = 0; t < nt; ++t) {
    int nodeBase = (b + t * TGRID) * 64;
#pragma unroll
    for (int i = 0; i < 2; ++i) {
      int tt = tid + i * 256;
      int row = tt >> 3, q = tt & 7;
      int g = nodeBase + row;
      s16x8 v = {};
      if (g < NN) v = A.h1[(size_t)g * 8 + q];
      *(s16x8*)&ht[t][row][q * 8] = v;
    }
  }

  // ======== phase A: fold BN1 -> W2, gemm2 + ReLU in place, stats S2/Q2 ========
  {
    if (tid < 64) {
      float mu = A.S1[tid] * (1.0f / NN);    // final (previous kernel completed)
      float var = A.Q1[tid] * (1.0f / NN) - mu * mu;
      float a = A.g1[tid] * rsqrtf(var + EPSV);
      lA[tid] = a; lC[tid] = A.be1[tid] - mu * a;
      ssum[tid] = 0.f; ssq[tid] = 0.f;
    }
    __syncthreads();
#pragma unroll
    for (int i = 0; i < 16; ++i) {
      int tt = tid + i * 256;
      lwf[tt >> 6][tt & 63] = f2bf(A.W2[tt] * lA[tt & 63]);
    }
    {
      int j = tid >> 2, p = tid & 3;
      const float* Wr = A.W2 + j * 64 + p * 16;
      float s = 0.f;
#pragma unroll
      for (int k = 0; k < 16; ++k) s += lC[p * 16 + k] * Wr[k];
      red[tid] = s;
    }
    __syncthreads();
    if (tid < 64) ld[tid] = A.b2[tid] + red[tid*4] + red[tid*4+1] + red[tid*4+2] + red[tid*4+3];
    __syncthreads();
    for (int t = 0; t < nt; ++t) {
      int nodeBase = (b + t * TGRID) * 64;
      f32x4 acc[4] = {{0,0,0,0},{0,0,0,0},{0,0,0,0},{0,0,0,0}};
#pragma unroll
      for (int s = 0; s < 2; ++s) {
        int k0 = 32 * s + rg * 8;
        s16x8 a = *(const s16x8*)&ht[t][w * 16 + ci][k0];
#pragma unroll
        for (int c = 0; c < 4; ++c) {
          s16x8 bb = *(const s16x8*)&lwf[c * 16 + ci][k0];
          acc[c] = __builtin_amdgcn_mfma_f32_16x16x32_bf16(a, bb, acc[c], 0, 0, 0);
        }
      }
#pragma unroll
      for (int c = 0; c < 4; ++c) {          // in place: wave owns its 16 rows
        int col = c * 16 + ci;
        float dd = ld[col];
        float ls = 0.f, lq = 0.f;
#pragma unroll
        for (int r = 0; r < 4; ++r) {
          int row = w * 16 + rg * 4 + r;
          float v = fmaxf(acc[c][r] + dd, 0.f);
          ht[t][row][col] = f2bf(v);
          if (nodeBase + row < NN) { ls += v; lq += v * v; }
        }
        atomicAdd(&ssum[col], ls);
        atomicAdd(&ssq[col], lq);
      }
    }
    __syncthreads();
    if (tid < 64) {
      unsafeAtomicAdd(&A.S2[tid], ssum[tid]);
      unsafeAtomicAdd(&A.Q2[tid], ssq[tid]);
    }
    __threadfence();
  }
  grid.sync();

  // ======== phase B: fold BN2 -> W3, gemm3 in place, stats S3/Q3 ========
  {
    if (tid < 64) {
      float Sv = atomicAdd(&A.S2[tid], 0.0f);   // coherent-point read
      float Qv = atomicAdd(&A.Q2[tid], 0.0f);
      float mu = Sv * (1.0f / NN);
      float var = Qv * (1.0f / NN) - mu * mu;
      float a = A.g2[tid] * rsqrtf(var + EPSV);
      lA[tid] = a; lC[tid] = A.be2[tid] - mu * a;
      ssum[tid] = 0.f; ssq[tid] = 0.f;
    }
    __syncthreads();
#pragma unroll
    for (int i = 0; i < 16; ++i) {
      int tt = tid + i * 256;
      lwf[tt >> 6][tt & 63] = f2bf(A.W3[tt] * lA[tt & 63]);
    }
    {
      int j = tid >> 2, p = tid & 3;
      const float* Wr = A.W3 + j * 64 + p * 16;
      float s = 0.f;
#pragma unroll
      for (int k = 0; k < 16; ++k) s += lC[p * 16 + k] * Wr[k];
      red[tid] = s;
    }
    __syncthreads();
    if (tid < 64) ld[tid] = A.b3[tid] + red[tid*4] + red[tid*4+1] + red[tid*4+2] + red[tid*4+3];
    __syncthreads();
    for (int t = 0; t < nt; ++t) {
      int nodeBase = (b + t * TGRID) * 64;
      f32x4 acc[4] = {{0,0,0,0},{0,0,0,0},{0,0,0,0},{0,0,0,0}};
#pragma unroll
      for (int s = 0; s < 2; ++s) {
        int k0 = 32 * s + rg * 8;
        s16x8 a = *(const s16x8*)&ht[t][w * 16 + ci][k0];
#pragma unroll
        for (int c = 0; c < 4; ++c) {
          s16x8 bb = *(const s16x8*)&lwf[c * 16 + ci][k0];
          acc[c] = __builtin_amdgcn_mfma_f32_16x16x32_bf16(a, bb, acc[c], 0, 0, 0);
        }
      }
#pragma unroll
      for (int c = 0; c < 4; ++c) {
        int col = c * 16 + ci;
        float dd = ld[col];
        float ls = 0.f, lq = 0.f;
#pragma unroll
        for (int r = 0; r < 4; ++r) {
          int row = w * 16 + rg * 4 + r;
          float v = acc[c][r] + dd;              // no ReLU
          ht[t][row][col] = f2bf(v);
          if (nodeBase + row < NN) { ls += v; lq += v * v; }
        }
        atomicAdd(&ssum[col], ls);
        atomicAdd(&ssq[col], lq);
      }
    }
    __syncthreads();
    if (tid < 64) {
      unsafeAtomicAdd(&A.S3[tid], ssum[tid]);
      unsafeAtomicAdd(&A.Q3[tid], ssq[tid]);
    }
    __threadfence();
  }
  grid.sync();

  // ======== phase C: BN3 normalize from LDS -> out (f32) ========
  {
    if (tid < 64) {
      float Sv = atomicAdd(&A.S3[tid], 0.0f);
      float Qv = atomicAdd(&A.Q3[tid], 0.0f);
      float mu = Sv * (1.0f / NN);
      float var = Qv * (1.0f / NN) - mu * mu;
      float a = A.g3[tid] * rsqrtf(var + EPSV);
      lA[tid] = a; lC[tid] = A.be3[tid] - mu * a;
    }
    __syncthreads();
    for (int t = 0; t < nt; ++t) {
      int nodeBase = (b + t * TGRID) * 64;
#pragma unroll
      for (int i = 0; i < 4; ++i) {
        int idx = tid + i * 256;
        int row = idx >> 4, q = idx & 15;
        int g = nodeBase + row;
        if (g < NN) {
          int k = q * 4;
          float4 o;
          o.x = bf2f(ht[t][row][k])     * lA[k]     + lC[k];
          o.y = bf2f(ht[t][row][k + 1]) * lA[k + 1] + lC[k + 1];
          o.z = bf2f(ht[t][row][k + 2]) * lA[k + 2] + lC[k + 2];
          o.w = bf2f(ht[t][row][k + 3]) * lA[k + 3] + lC[k + 3];
          A.out4[(size_t)g * 16 + q] = o;
        }
      }
    }
  }
}

// ---- Fallback split tail (r13-proven): gemm w/ BN fold + bn3 ------------------
template <bool RELU>
__global__ __launch_bounds__(256) void k_gemm64f(
    const s16x8* __restrict__ A8, const float* __restrict__ Wf,
    const float* __restrict__ bias,
    const float* __restrict__ gm, const float* __restrict__ bt,
    const float* __restrict__ Sin, const float* __restrict__ Qin,
    unsigned short* __restrict__ Obf,
    float* __restrict__ Sout, float* __restrict__ Qout) {
  __shared__ unsigned short la[64][72];
  __shared__ unsigned short lwf[64][72];
  __shared__ float lA[64], lC[64], ld[64], red[256], ssum[64], ssq[64];
  const int tid = threadIdx.x;
  const int nodeBase = blockIdx.x * 64;
  if (tid < 64) {
    float mu = Sin[tid] * (1.0f / NN);
    float var = Qin[tid] * (1.0f / NN) - mu * mu;
    float a = gm[tid] * rsqrtf(var + EPSV);
    lA[tid] = a; lC[tid] = bt[tid] - mu * a;
    ssum[tid] = 0.f; ssq[tid] = 0.f;
  }
  __syncthreads();
#pragma unroll
  for (int i = 0; i < 2; ++i) {
    int t = tid + i * 256;
    int row = t >> 3, q = t & 7;
    int g = nodeBase + row;
    s16x8 v = {};
    if (g < NN) v = A8[(size_t)g * 8 + q];
    *(s16x8*)&la[row][q * 8] = v;
  }
#pragma unroll
  for (int i = 0; i < 16; ++i) {
    int t = tid + i * 256;
    lwf[t >> 6][t & 63] = f2bf(Wf[t] * lA[t & 63]);
  }
  {
    int j = tid >> 2, p = tid & 3;
    const float* Wr = Wf + j * 64 + p * 16;
    float s = 0.f;
#pragma unroll
    for (int k = 0; k < 16; ++k) s += lC[p * 16 + k] * Wr[k];
    red[tid] = s;
  }
  __syncthreads();
  if (tid < 64) ld[tid] = bias[tid] + red[tid*4] + red[tid*4+1] + red[tid*4+2] + red[tid*4+3];
  __syncthreads();
  const int lane = tid & 63, w = tid >> 6;
  const int rg = lane >> 4, ci = lane & 15;
  f32x4 acc[4] = {{0,0,0,0},{0,0,0,0},{0,0,0,0},{0,0,0,0}};
#pragma unroll
  for (int s = 0; s < 2; ++s) {
    int k0 = 32 * s + rg * 8;
    s16x8 a = *(const s16x8*)&la[w * 16 + ci][k0];
#pragma unroll
    for (int c = 0; c < 4; ++c) {
      s16x8 b = *(const s16x8*)&lwf[c * 16 + ci][k0];
      acc[c] = __builtin_amdgcn_mfma_f32_16x16x32_bf16(a, b, acc[c], 0, 0, 0);
    }
  }
  __syncthreads();
  unsigned short (*lo)[72] = (unsigned short(*)[72])la;
#pragma unroll
  for (int c = 0; c < 4; ++c) {
    int col = c * 16 + ci;
    float dd = ld[col];
    float ls = 0.f, lq = 0.f;
#pragma unroll
    for (int r = 0; r < 4; ++r) {
      int row = w * 16 + rg * 4 + r;
      float v = acc[c][r] + dd;
      if (RELU) v = fmaxf(v, 0.f);
      lo[row][col] = f2bf(v);
      if (nodeBase + row < NN) { ls += v; lq += v * v; }
    }
    atomicAdd(&ssum[col], ls);
    atomicAdd(&ssq[col], lq);
  }
  __syncthreads();
#pragma unroll
  for (int i = 0; i < 2; ++i) {
    int t = tid + i * 256;
    int row = t >> 3, q = t & 7;
    int g = nodeBase + row;
    if (g < NN) *(s16x8*)&Obf[(size_t)g * 64 + q * 8] = *(const s16x8*)&lo[row][q * 8];
  }
  if (tid < 64) {
    unsafeAtomicAdd(&Sout[tid], ssum[tid]);
    unsafeAtomicAdd(&Qout[tid], ssq[tid]);
  }
}

__global__ __launch_bounds__(256) void k_bn3(
    const s16x8* __restrict__ h3b, const float* __restrict__ gm,
    const float* __restrict__ bt, const float* __restrict__ S,
    const float* __restrict__ Q, float4* __restrict__ out) {
  __shared__ float lA[64], lC[64];
  const int tid = threadIdx.x;
  if (tid < 64) {
    float mu = S[tid] * (1.0f / NN);
    float var = Q[tid] * (1.0f / NN) - mu * mu;
    float a = gm[tid] * rsqrtf(var + EPSV);
    lA[tid] = a;
    lC[tid] = bt[tid] - mu * a;
  }
  __syncthreads();
  const int total = NN * 8;
  for (int idx = blockIdx.x * 256 + tid; idx < total; idx += gridDim.x * 256) {
    s16x8 v = h3b[idx];
    int k = (idx & 7) * 8;
    float4 o0, o1;
    o0.x = bf2f((unsigned short)v[0]) * lA[k]     + lC[k];
    o0.y = bf2f((unsigned short)v[1]) * lA[k + 1] + lC[k + 1];
    o0.z = bf2f((unsigned short)v[2]) * lA[k + 2] + lC[k + 2];
    o0.w = bf2f((unsigned short)v[3]) * lA[k + 3] + lC[k + 3];
    o1.x = bf2f((unsigned short)v[4]) * lA[k + 4] + lC[k + 4];
    o1.y = bf2f((unsigned short)v[5]) * lA[k + 5] + lC[k + 5];
    o1.z = bf2f((unsigned short)v[6]) * lA[k + 6] + lC[k + 6];
    o1.w = bf2f((unsigned short)v[7]) * lA[k + 7] + lC[k + 7];
    out[idx * 2]     = o0;
    out[idx * 2 + 1] = o1;
  }
}

extern "C" void kernel_launch(void* const* d_in, const int* in_sizes, int n_in,
                              void* d_out, int out_size, void* d_ws, size_t ws_size,
                              hipStream_t stream) {
  const float* x     = (const float*)d_in[0];
  const int*   ei    = (const int*)d_in[1];
  const float* ea    = (const float*)d_in[2];
  const float* state = (const float*)d_in[3];
  const int*   batch = (const int*)d_in[4];

  // Workspace layout:
  //   [0,        400000)   cnt
  //   [400000,   401536)   stats S1 Q1 S2 Q2 S3 Q3
  //   [401536,  26018432)  eids (int, 64/node)
  //   [26018432,38818432)  h1 bf16
  //   [38818432,64418432)  ph f32 partial
  //   [64418432,77218432)  h2 bf16 (fallback path only)
  //   [77218432,90018432)  h3 bf16 (fallback path only)
  char* ws = (char*)d_ws;
  int*   cnt  = (int*)ws;
  float* S1   = (float*)(ws + 400000);
  float* Q1 = S1 + 64;
  float* S2 = S1 + 128;
  float* Q2 = S1 + 192;
  float* S3 = S1 + 256;
  float* Q3 = S1 + 320;
  int*            eids = (int*)(ws + 401536);
  unsigned short* h1   = (unsigned short*)(ws + 26018432);
  f32x4*          ph   = (f32x4*)(ws + 38818432);
  unsigned short* h2   = (unsigned short*)(ws + 64418432);
  unsigned short* h3b  = (unsigned short*)(ws + 77218432);

  hipMemsetAsync(ws, 0, 401536, stream);   // cnt + stats

  k_bucket_g1a<<<6250 + NTILE, 256, 0, stream>>>(
      ei, cnt, eids, (const float4*)x, (const float4*)state, batch,
      (const float4*)d_in[5], ph);
  k_gather_g1b<<<NTILE, 256, 0, stream>>>(cnt, eids, (const float4*)ea,
                                          (const float4*)d_in[5],
                                          (const float*)d_in[6], ph, h1, S1, Q1);
  TailArgs ta;
  ta.h1 = (const s16x8*)h1;
  ta.W2 = (const float*)d_in[9];  ta.b2 = (const float*)d_in[10];
  ta.g1 = (const float*)d_in[7];  ta.be1 = (const float*)d_in[8];
  ta.W3 = (const float*)d_in[13]; ta.b3 = (const float*)d_in[14];
  ta.g2 = (const float*)d_in[11]; ta.be2 = (const float*)d_in[12];
  ta.g3 = (const float*)d_in[15]; ta.be3 = (const float*)d_in[16];
  ta.S1 = S1; ta.Q1 = Q1; ta.S2 = S2; ta.Q2 = Q2; ta.S3 = S3; ta.Q3 = Q3;
  ta.out4 = (float4*)d_out;
  void* kargs[] = {&ta};
  hipError_t rc = hipLaunchCooperativeKernel((const void*)k_tail, dim3(TGRID),
                                             dim3(256), kargs, 0u, stream);
  if (rc != hipSuccess) {
    // fallback: r13-proven split tail (same math, same outputs)
    k_gemm64f<true><<<NTILE, 256, 0, stream>>>(
        (const s16x8*)h1, (const float*)d_in[9], (const float*)d_in[10],
        (const float*)d_in[7], (const float*)d_in[8], S1, Q1, h2, S2, Q2);
    k_gemm64f<false><<<NTILE, 256, 0, stream>>>(
        (const s16x8*)h2, (const float*)d_in[13], (const float*)d_in[14],
        (const float*)d_in[11], (const float*)d_in[12], S2, Q2, h3b, S3, Q3);
    k_bn3<<<2048, 256, 0, stream>>>((const s16x8*)h3b, (const float*)d_in[15],
                                    (const float*)d_in[16], S3, Q3, (float4*)d_out);
  }
}

// Round 16
// 345.211 us; speedup vs baseline: 1.3616x; 1.3616x over previous
//
#include <hip/hip_runtime.h>

#define NN 100000
#define NE 1600000
#define EPSV 1e-5f
#define NTILE 1563          // ceil(NN/64)

typedef float f32x4 __attribute__((ext_vector_type(4)));
typedef short s16x8 __attribute__((ext_vector_type(8)));

__device__ __forceinline__ unsigned short f2bf(float f) {
  unsigned int u = __float_as_uint(f);
  u += 0x7fffu + ((u >> 16) & 1u);   // round-to-nearest-even
  return (unsigned short)(u >> 16);
}

__device__ __forceinline__ float bf2f(unsigned short s) {
  return __uint_as_float(((unsigned int)s) << 16);
}

__device__ __forceinline__ ushort4 pack4(float4 v) {
  ushort4 s;
  s.x = f2bf(v.x); s.y = f2bf(v.y); s.z = f2bf(v.z); s.w = f2bf(v.w);
  return s;
}

// ---- K1: bucket (4/5 of blocks) ∥ g1a partial GEMM (1/5) ----------------------
__global__ __launch_bounds__(256) void k_bucket_g1a(
    const int* __restrict__ ei, int* __restrict__ cnt, int* __restrict__ eids,
    const float4* __restrict__ x4, const float4* __restrict__ state4,
    const int* __restrict__ batch, const float4* __restrict__ w14,
    f32x4* __restrict__ ph) {
  __shared__ unsigned short lx[64][136];   // x(0..63) + state(64..127) per node
  __shared__ unsigned short lw[64][136];   // W1 x-cols + state-cols per out-row
  const int idx = blockIdx.x;
  const int tid = threadIdx.x;
  const bool is_g1a = ((idx % 5) == 2) && (idx / 5 < NTILE);
  if (!is_g1a) {
    int nga = idx / 5 + (((idx % 5) > 2) ? 1 : 0);   // g1a blocks before idx
    if (nga > NTILE) nga = NTILE;
    int e = (idx - nga) * 256 + tid;                 // bucket_id * 256 + tid
    int src = ei[e];
    int pos = atomicAdd(&cnt[src], 1);
    if (pos < 64) eids[(size_t)src * 64 + pos] = e;
    return;
  }
  const int tile = idx / 5;
  const int nodeBase = tile * 64;
#pragma unroll
  for (int i = 0; i < 4; ++i) {            // W1: x-part q0..15, state-part q32..47
    int t = tid + i * 256;
    int j = t >> 4, q = t & 15;
    *(ushort4*)&lw[j][q * 4]      = pack4(w14[j * 48 + q]);
    *(ushort4*)&lw[j][64 + q * 4] = pack4(w14[j * 48 + 32 + q]);
  }
#pragma unroll
  for (int i = 0; i < 4; ++i) {            // node tile: x + state[batch]
    int t = tid + i * 256;
    int node = t >> 4, q = t & 15;
    int g = nodeBase + node;
    float4 vx = {0,0,0,0}, vs = {0,0,0,0};
    if (g < NN) {
      vx = x4[(size_t)g * 16 + q];
      vs = state4[batch[g] * 16 + q];
    }
    *(ushort4*)&lx[node][q * 4]      = pack4(vx);
    *(ushort4*)&lx[node][64 + q * 4] = pack4(vs);
  }
  __syncthreads();
  const int lane = tid & 63, w = tid >> 6;
  const int rg = lane >> 4, ci = lane & 15;
  f32x4 acc[4] = {{0,0,0,0},{0,0,0,0},{0,0,0,0},{0,0,0,0}};
#pragma unroll
  for (int s = 0; s < 4; ++s) {            // 128 packed k-cols
    int k0 = 32 * s + rg * 8;
    s16x8 a = *(const s16x8*)&lx[w * 16 + ci][k0];
#pragma unroll
    for (int c = 0; c < 4; ++c) {
      s16x8 b = *(const s16x8*)&lw[c * 16 + ci][k0];
      acc[c] = __builtin_amdgcn_mfma_f32_16x16x32_bf16(a, b, acc[c], 0, 0, 0);
    }
  }
#pragma unroll
  for (int c = 0; c < 4; ++c)
    ph[(size_t)tile * 1024 + tid * 4 + c] = acc[c];
}

// ---- K2: fused gather-mean + g1b: one block per 64-node tile -------------------
__global__ __launch_bounds__(256) void k_gather_g1b(
    const int* __restrict__ cnt, const int* __restrict__ eids,
    const float4* __restrict__ ea4,
    const float4* __restrict__ w14, const float* __restrict__ b1,
    const f32x4* __restrict__ ph, unsigned short* __restrict__ h1,
    float* __restrict__ Sout, float* __restrict__ Qout) {
  __shared__ unsigned short lv[64][72];    // vmean tile
  __shared__ unsigned short lwv[64][72];   // W1 vm-cols; reused as out-tile
  __shared__ float ssum[64], ssq[64];
  const int tid = threadIdx.x;
  const int tile = blockIdx.x;
  const int nodeBase = tile * 64;
  if (tid < 64) { ssum[tid] = 0.f; ssq[tid] = 0.f; }
#pragma unroll
  for (int i = 0; i < 4; ++i) {            // W1 vm-cols (k=64..127)
    int t = tid + i * 256;
    int j = t >> 4, q = t & 15;
    *(ushort4*)&lwv[j][q * 4] = pack4(w14[j * 48 + 16 + q]);
  }
  const int lane = tid & 63, w = tid >> 6;
  const int grp = lane >> 4, q = lane & 15;
  for (int k = 0; k < 16; ++k) {           // 16 nodes per wave
    int n = nodeBase + w * 16 + k;
    float ax = 0.f, ay = 0.f, az = 0.f, aw = 0.f;
    int c = 0;
    if (n < NN) {
      const int* elist = eids + (size_t)n * 64;
      c = cnt[n];
      int m = c < 64 ? c : 64;
      int rm = m - 1;
      {
        int r0 = grp,      r1 = 4 + grp,  r2 = 8 + grp,  r3 = 12 + grp;
        int r4 = 16 + grp, r5 = 20 + grp, r6 = 24 + grp, r7 = 28 + grp;
        int i0 = elist[r0 < m ? r0 : rm];
        int i1 = elist[r1 < m ? r1 : rm];
        int i2 = elist[r2 < m ? r2 : rm];
        int i3 = elist[r3 < m ? r3 : rm];
        int i4 = elist[r4 < m ? r4 : rm];
        int i5 = elist[r5 < m ? r5 : rm];
        int i6 = elist[r6 < m ? r6 : rm];
        int i7 = elist[r7 < m ? r7 : rm];
        float4 v0 = ea4[(size_t)i0 * 16 + q];
        float4 v1 = ea4[(size_t)i1 * 16 + q];
        float4 v2 = ea4[(size_t)i2 * 16 + q];
        float4 v3 = ea4[(size_t)i3 * 16 + q];
        float4 v4 = ea4[(size_t)i4 * 16 + q];
        float4 v5 = ea4[(size_t)i5 * 16 + q];
        float4 v6 = ea4[(size_t)i6 * 16 + q];
        float4 v7 = ea4[(size_t)i7 * 16 + q];
        float m0 = r0 < m ? 1.f : 0.f, m1 = r1 < m ? 1.f : 0.f;
        float m2 = r2 < m ? 1.f : 0.f, m3 = r3 < m ? 1.f : 0.f;
        ax += m0 * v0.x + m1 * v1.x + m2 * v2.x + m3 * v3.x;
        ay += m0 * v0.y + m1 * v1.y + m2 * v2.y + m3 * v3.y;
        az += m0 * v0.z + m1 * v1.z + m2 * v2.z + m3 * v3.z;
        aw += m0 * v0.w + m1 * v1.w + m2 * v2.w + m3 * v3.w;
        float m4 = r4 < m ? 1.f : 0.f, m5 = r5 < m ? 1.f : 0.f;
        float m6 = r6 < m ? 1.f : 0.f, m7 = r7 < m ? 1.f : 0.f;
        ax += m4 * v4.x + m5 * v5.x + m6 * v6.x + m7 * v7.x;
        ay += m4 * v4.y + m5 * v5.y + m6 * v6.y + m7 * v7.y;
        az += m4 * v4.z + m5 * v5.z + m6 * v6.z + m7 * v7.z;
        aw += m4 * v4.w + m5 * v5.w + m6 * v6.w + m7 * v7.w;
      }
      if (m > 32) {                        // rare tail (P ~ 2e-4)
        for (int e = 32; e < m; e += 16) {
          int r0 = e + grp, r1 = e + 4 + grp, r2 = e + 8 + grp, r3 = e + 12 + grp;
          int i0 = elist[r0 < m ? r0 : rm];
          int i1 = elist[r1 < m ? r1 : rm];
          int i2 = elist[r2 < m ? r2 : rm];
          int i3 = elist[r3 < m ? r3 : rm];
          float4 v0 = ea4[(size_t)i0 * 16 + q];
          float4 v1 = ea4[(size_t)i1 * 16 + q];
          float4 v2 = ea4[(size_t)i2 * 16 + q];
          float4 v3 = ea4[(size_t)i3 * 16 + q];
          float m0 = r0 < m ? 1.f : 0.f, m1 = r1 < m ? 1.f : 0.f;
          float m2 = r2 < m ? 1.f : 0.f, m3 = r3 < m ? 1.f : 0.f;
          ax += m0 * v0.x + m1 * v1.x + m2 * v2.x + m3 * v3.x;
          ay += m0 * v0.y + m1 * v1.y + m2 * v2.y + m3 * v3.y;
          az += m0 * v0.z + m1 * v1.z + m2 * v2.z + m3 * v3.z;
          aw += m0 * v0.w + m1 * v1.w + m2 * v2.w + m3 * v3.w;
        }
      }
    }
    ax += __shfl_xor(ax, 16); ay += __shfl_xor(ay, 16);
    az += __shfl_xor(az, 16); aw += __shfl_xor(aw, 16);
    ax += __shfl_xor(ax, 32); ay += __shfl_xor(ay, 32);
    az += __shfl_xor(az, 32); aw += __shfl_xor(aw, 32);
    if (lane < 16) {
      float inv = 1.0f / fmaxf((float)c, 1.0f);
      float4 r; r.x = ax * inv; r.y = ay * inv; r.z = az * inv; r.w = aw * inv;
      *(ushort4*)&lv[w * 16 + k][lane * 4] = pack4(r);
    }
  }
  __syncthreads();
  const int rg = lane >> 4, ci = lane & 15;
  f32x4 acc[4];
#pragma unroll
  for (int cc = 0; cc < 4; ++cc) acc[cc] = ph[(size_t)tile * 1024 + tid * 4 + cc];
#pragma unroll
  for (int s = 0; s < 2; ++s) {
    int k0 = 32 * s + rg * 8;
    s16x8 a = *(const s16x8*)&lv[w * 16 + ci][k0];
#pragma unroll
    for (int cc = 0; cc < 4; ++cc) {
      s16x8 b = *(const s16x8*)&lwv[cc * 16 + ci][k0];
      acc[cc] = __builtin_amdgcn_mfma_f32_16x16x32_bf16(a, b, acc[cc], 0, 0, 0);
    }
  }
  __syncthreads();                         // lwv reads done; reuse as out-tile
  unsigned short (*lo)[72] = (unsigned short(*)[72])lwv;
#pragma unroll
  for (int cc = 0; cc < 4; ++cc) {
    int col = cc * 16 + ci;
    float bb = b1[col];
    float ls = 0.f, lq = 0.f;
#pragma unroll
    for (int r = 0; r < 4; ++r) {
      int row = w * 16 + rg * 4 + r;
      float v = fmaxf(acc[cc][r] + bb, 0.f);
      lo[row][col] = f2bf(v);
      if (nodeBase + row < NN) { ls += v; lq += v * v; }
    }
    atomicAdd(&ssum[col], ls);
    atomicAdd(&ssq[col], lq);
  }
  __syncthreads();
#pragma unroll
  for (int i = 0; i < 2; ++i) {            // coalesced 16B stores
    int t = tid + i * 256;
    int row = t >> 3, q2 = t & 7;
    int g = nodeBase + row;
    if (g < NN) *(s16x8*)&h1[(size_t)g * 64 + q2 * 8] = *(const s16x8*)&lo[row][q2 * 8];
  }
  if (tid < 64) {
    unsafeAtomicAdd(&Sout[tid], ssum[tid]);
    unsafeAtomicAdd(&Qout[tid], ssq[tid]);
  }
}

// ---- GEMM2/3 with in-kernel BN fold: out = [relu](A @ Wf^T + d) ---------------
template <bool RELU>
__global__ __launch_bounds__(256) void k_gemm64f(
    const s16x8* __restrict__ A8,     // bf16 [NN][64]
    const float* __restrict__ Wf,     // f32 [64][64] raw weights
    const float* __restrict__ bias,
    const float* __restrict__ gm, const float* __restrict__ bt,
    const float* __restrict__ Sin, const float* __restrict__ Qin,
    unsigned short* __restrict__ Obf,
    float* __restrict__ Sout, float* __restrict__ Qout) {
  __shared__ unsigned short la[64][72];    // A tile; reused as out-tile
  __shared__ unsigned short lwf[64][72];   // folded W bf16
  __shared__ float lA[64], lC[64], ld[64], red[256], ssum[64], ssq[64];
  const int tid = threadIdx.x;
  const int nodeBase = blockIdx.x * 64;
  if (tid < 64) {
    float mu = Sin[tid] * (1.0f / NN);
    float var = Qin[tid] * (1.0f / NN) - mu * mu;
    float a = gm[tid] * rsqrtf(var + EPSV);
    lA[tid] = a; lC[tid] = bt[tid] - mu * a;
    ssum[tid] = 0.f; ssq[tid] = 0.f;
  }
  __syncthreads();
#pragma unroll
  for (int i = 0; i < 2; ++i) {            // A tile: 512 x 16B
    int t = tid + i * 256;
    int row = t >> 3, q = t & 7;
    int g = nodeBase + row;
    s16x8 v = {};
    if (g < NN) v = A8[(size_t)g * 8 + q];
    *(s16x8*)&la[row][q * 8] = v;
  }
#pragma unroll
  for (int i = 0; i < 16; ++i) {           // fold weights by BN scale a_k
    int t = tid + i * 256;
    lwf[t >> 6][t & 63] = f2bf(Wf[t] * lA[t & 63]);
  }
  {                                        // folded bias partials
    int j = tid >> 2, p = tid & 3;
    const float* Wr = Wf + j * 64 + p * 16;
    float s = 0.f;
#pragma unroll
    for (int k = 0; k < 16; ++k) s += lC[p * 16 + k] * Wr[k];
    red[tid] = s;
  }
  __syncthreads();
  if (tid < 64) ld[tid] = bias[tid] + red[tid*4] + red[tid*4+1] + red[tid*4+2] + red[tid*4+3];
  __syncthreads();
  const int lane = tid & 63, w = tid >> 6;
  const int rg = lane >> 4, ci = lane & 15;
  f32x4 acc[4] = {{0,0,0,0},{0,0,0,0},{0,0,0,0},{0,0,0,0}};
#pragma unroll
  for (int s = 0; s < 2; ++s) {
    int k0 = 32 * s + rg * 8;
    s16x8 a = *(const s16x8*)&la[w * 16 + ci][k0];
#pragma unroll
    for (int c = 0; c < 4; ++c) {
      s16x8 b = *(const s16x8*)&lwf[c * 16 + ci][k0];
      acc[c] = __builtin_amdgcn_mfma_f32_16x16x32_bf16(a, b, acc[c], 0, 0, 0);
    }
  }
  __syncthreads();                         // reuse la as out-tile
  unsigned short (*lo)[72] = (unsigned short(*)[72])la;
#pragma unroll
  for (int c = 0; c < 4; ++c) {
    int col = c * 16 + ci;
    float dd = ld[col];
    float ls = 0.f, lq = 0.f;
#pragma unroll
    for (int r = 0; r < 4; ++r) {
      int row = w * 16 + rg * 4 + r;
      float v = acc[c][r] + dd;
      if (RELU) v = fmaxf(v, 0.f);
      lo[row][col] = f2bf(v);
      if (nodeBase + row < NN) { ls += v; lq += v * v; }
    }
    atomicAdd(&ssum[col], ls);
    atomicAdd(&ssq[col], lq);
  }
  __syncthreads();
#pragma unroll
  for (int i = 0; i < 2; ++i) {
    int t = tid + i * 256;
    int row = t >> 3, q = t & 7;
    int g = nodeBase + row;
    if (g < NN) *(s16x8*)&Obf[(size_t)g * 64 + q * 8] = *(const s16x8*)&lo[row][q * 8];
  }
  if (tid < 64) {
    unsafeAtomicAdd(&Sout[tid], ssum[tid]);
    unsafeAtomicAdd(&Qout[tid], ssq[tid]);
  }
}

// ---- final BN3 elementwise (bf16 in, f32 out) ---------------------------------
__global__ __launch_bounds__(256) void k_bn3(
    const s16x8* __restrict__ h3b, const float* __restrict__ gm,
    const float* __restrict__ bt, const float* __restrict__ S,
    const float* __restrict__ Q, float4* __restrict__ out) {
  __shared__ float lA[64], lC[64];
  const int tid = threadIdx.x;
  if (tid < 64) {
    float mu = S[tid] * (1.0f / NN);
    float var = Q[tid] * (1.0f / NN) - mu * mu;
    float a = gm[tid] * rsqrtf(var + EPSV);
    lA[tid] = a;
    lC[tid] = bt[tid] - mu * a;
  }
  __syncthreads();
  const int total = NN * 8;                // short8 units
  for (int idx = blockIdx.x * 256 + tid; idx < total; idx += gridDim.x * 256) {
    s16x8 v = h3b[idx];
    int k = (idx & 7) * 8;
    float4 o0, o1;
    o0.x = bf2f((unsigned short)v[0]) * lA[k]     + lC[k];
    o0.y = bf2f((unsigned short)v[1]) * lA[k + 1] + lC[k + 1];
    o0.z = bf2f((unsigned short)v[2]) * lA[k + 2] + lC[k + 2];
    o0.w = bf2f((unsigned short)v[3]) * lA[k + 3] + lC[k + 3];
    o1.x = bf2f((unsigned short)v[4]) * lA[k + 4] + lC[k + 4];
    o1.y = bf2f((unsigned short)v[5]) * lA[k + 5] + lC[k + 5];
    o1.z = bf2f((unsigned short)v[6]) * lA[k + 6] + lC[k + 6];
    o1.w = bf2f((unsigned short)v[7]) * lA[k + 7] + lC[k + 7];
    out[idx * 2]     = o0;
    out[idx * 2 + 1] = o1;
  }
}

extern "C" void kernel_launch(void* const* d_in, const int* in_sizes, int n_in,
                              void* d_out, int out_size, void* d_ws, size_t ws_size,
                              hipStream_t stream) {
  const float* x     = (const float*)d_in[0];
  const int*   ei    = (const int*)d_in[1];
  const float* ea    = (const float*)d_in[2];
  const float* state = (const float*)d_in[3];
  const int*   batch = (const int*)d_in[4];

  // Workspace layout:
  //   [0,        400000)   cnt
  //   [400000,   401536)   stats S1 Q1 S2 Q2 S3 Q3
  //   [401536,  26018432)  eids (int, 64/node)   == h3 bf16 alias (12.8 MB)
  //   [26018432,38818432)  h2 bf16
  //   [38818432,51618432)  h1 bf16
  //   [51618432,77218432)  ph f32 partial (g1a -> gather_g1b)
  char* ws = (char*)d_ws;
  int*   cnt  = (int*)ws;
  float* S1   = (float*)(ws + 400000);
  float* Q1 = S1 + 64;
  float* S2 = S1 + 128;
  float* Q2 = S1 + 192;
  float* S3 = S1 + 256;
  float* Q3 = S1 + 320;
  int*            eids = (int*)(ws + 401536);
  unsigned short* h3b  = (unsigned short*)(ws + 401536);   // alias eids
  unsigned short* h2   = (unsigned short*)(ws + 26018432);
  unsigned short* h1   = (unsigned short*)(ws + 38818432);
  f32x4*          ph   = (f32x4*)(ws + 51618432);

  hipMemsetAsync(ws, 0, 401536, stream);   // cnt + stats

  k_bucket_g1a<<<6250 + NTILE, 256, 0, stream>>>(
      ei, cnt, eids, (const float4*)x, (const float4*)state, batch,
      (const float4*)d_in[5], ph);
  k_gather_g1b<<<NTILE, 256, 0, stream>>>(cnt, eids, (const float4*)ea,
                                          (const float4*)d_in[5],
                                          (const float*)d_in[6], ph, h1, S1, Q1);
  k_gemm64f<true><<<NTILE, 256, 0, stream>>>(
      (const s16x8*)h1, (const float*)d_in[9], (const float*)d_in[10],
      (const float*)d_in[7], (const float*)d_in[8], S1, Q1, h2, S2, Q2);
  k_gemm64f<false><<<NTILE, 256, 0, stream>>>(
      (const s16x8*)h2, (const float*)d_in[13], (const float*)d_in[14],
      (const float*)d_in[11], (const float*)d_in[12], S2, Q2, h3b, S3, Q3);
  k_bn3<<<2048, 256, 0, stream>>>((const s16x8*)h3b, (const float*)d_in[15],
                                  (const float*)d_in[16], S3, Q3, (float4*)d_out);
}